// Round 7
// baseline (344.310 us; speedup 1.0000x reference)
//
#include <hip/hip_runtime.h>
#include <hip/hip_bf16.h>
#include <hip/hip_cooperative_groups.h>

namespace cg = cooperative_groups;

#define IN_DIM 2048
#define OUT_DIM 2048
#define NE 8
#define M_TOT 8192          // B*S = 4*2048
#define RANK_PAD 128        // 8 shared + 64 expert + 24 zero + 32 align pad
#define K_EXT 2176          // IN_DIM + RANK_PAD, divisible by 64

typedef short short8 __attribute__((ext_vector_type(8)));
typedef float floatx4 __attribute__((ext_vector_type(4)));
typedef unsigned short us;

__device__ __forceinline__ us f2bf(float f) {
    __hip_bfloat16 h = __float2bfloat16(f);   // native RNE cast
    return *reinterpret_cast<us*>(&h);
}

__device__ __forceinline__ short8 cvt8(float4 v0, float4 v1) {
    short8 o;
    o[0] = (short)f2bf(v0.x); o[1] = (short)f2bf(v0.y);
    o[2] = (short)f2bf(v0.z); o[3] = (short)f2bf(v0.w);
    o[4] = (short)f2bf(v1.x); o[5] = (short)f2bf(v1.y);
    o[6] = (short)f2bf(v1.z); o[7] = (short)f2bf(v1.w);
    return o;
}

__device__ __forceinline__ void gld_lds16(const void* g, void* l) {
    __builtin_amdgcn_global_load_lds(
        (const __attribute__((address_space(1))) void*)g,
        (__attribute__((address_space(3))) void*)l, 16, 0, 0);
}

// ---------------------------------------------------------------------------
// Main-GEMM machinery (EXACT R4/R6 schedule: 256x256 tile, 8-phase read-ahead,
// counted lgkm(4/8), vmcnt(8) at p0/p2, slot swizzle ps = s ^ ((row>>1)&3)
// both sides, XCD-chunked block swizzle). Proven: 68.4us, 0 bank conflicts.
// ---------------------------------------------------------------------------

__device__ __forceinline__ void stage2(const us* src, char* lds) {
    gld_lds16(src, lds);
    gld_lds16(src + 128 * K_EXT, lds + 8192);
}

__device__ __forceinline__ void mfma_quad(floatx4 (&acc)[8][4], const short8 (&af)[4],
                                          const short8 (&bf)[4], int mq) {
#pragma unroll
    for (int i = 0; i < 4; ++i)
#pragma unroll
        for (int ni = 0; ni < 4; ++ni)
            acc[mq * 4 + i][ni] =
                __builtin_amdgcn_mfma_f32_16x16x32_bf16(af[i], bf[ni], acc[mq * 4 + i][ni], 0, 0, 0);
}

template <int SM, int VM0, int VM2, bool RD3>
__device__ __forceinline__ void ktile(
    const us* __restrict__ pA, const us* __restrict__ pB, int k1, int k2,
    const char* smC, const char* smN, char* lwC, char* lwN,
    int ab, int bb,
    short8 (&afA)[4], short8 (&afB)[4], short8 (&bfA)[4], short8 (&bfB)[4],
    floatx4 (&acc)[8][4])
{
    // ---------- p0 ----------
#pragma unroll
    for (int i = 0; i < 4; ++i) afB[i] = *(const short8*)(smC + ab + (4 + i) * 1024);
    asm volatile("s_waitcnt lgkmcnt(4)" ::: "memory");
    __builtin_amdgcn_sched_barrier(0);
    __builtin_amdgcn_s_setprio(1);
    mfma_quad(acc, afA, bfA, 0);
    __builtin_amdgcn_s_setprio(0);
    if (SM & 1) stage2(pA + k1 + 32, lwN + 32768);
    if (VM0 == 8)      asm volatile("s_waitcnt vmcnt(8)" ::: "memory");
    else if (VM0 == 0) asm volatile("s_waitcnt vmcnt(0)" ::: "memory");
    __builtin_amdgcn_s_barrier();

    // ---------- p1 ----------
#pragma unroll
    for (int i = 0; i < 4; ++i) afA[i] = *(const short8*)(smC + 32768 + ab + (4 + i) * 1024);
#pragma unroll
    for (int i = 0; i < 4; ++i) bfB[i] = *(const short8*)(smC + 32768 + bb + i * 1024);
    asm volatile("s_waitcnt lgkmcnt(8)" ::: "memory");
    __builtin_amdgcn_sched_barrier(0);
    __builtin_amdgcn_s_setprio(1);
    mfma_quad(acc, afB, bfA, 1);
    __builtin_amdgcn_s_setprio(0);
    if (SM & 2) stage2(pB + k2, lwC + 16384);
    __builtin_amdgcn_s_barrier();

    // ---------- p2 ----------
#pragma unroll
    for (int i = 0; i < 4; ++i) afB[i] = *(const short8*)(smC + 32768 + ab + i * 1024);
    asm volatile("s_waitcnt lgkmcnt(4)" ::: "memory");
    __builtin_amdgcn_sched_barrier(0);
    __builtin_amdgcn_s_setprio(1);
    mfma_quad(acc, afA, bfB, 1);
    __builtin_amdgcn_s_setprio(0);
    if (SM & 4) stage2(pA + k2, lwC);
    if (VM2 == 8)      asm volatile("s_waitcnt vmcnt(8)" ::: "memory");
    else if (VM2 == 4) asm volatile("s_waitcnt vmcnt(4)" ::: "memory");
    __builtin_amdgcn_s_barrier();

    // ---------- p3 ----------
    if (RD3) {
#pragma unroll
        for (int i = 0; i < 4; ++i) afA[i] = *(const short8*)(smN + ab + i * 1024);
#pragma unroll
        for (int i = 0; i < 4; ++i) bfA[i] = *(const short8*)(smN + bb + i * 1024);
        asm volatile("s_waitcnt lgkmcnt(8)" ::: "memory");
    } else {
        asm volatile("s_waitcnt lgkmcnt(0)" ::: "memory");
    }
    __builtin_amdgcn_sched_barrier(0);
    __builtin_amdgcn_s_setprio(1);
    mfma_quad(acc, afB, bfB, 0);
    __builtin_amdgcn_s_setprio(0);
    if (SM & 8) stage2(pB + k2 + 32, lwC + 49152);
    __builtin_amdgcn_s_barrier();
}

__device__ void run_main_gemm(char* smem, int tid, int bid,
                              const us* __restrict__ A, const us* __restrict__ B,
                              const float* __restrict__ bias, float* __restrict__ out) {
    int lane = tid & 63, w = tid >> 6;
    int wm = w >> 2, wn = w & 3;
    int rlo = lane & 15, kq = lane >> 4;

    // XCD-chunked swizzle: 256 blocks = 8 XCDs x 32
    int bs = (bid & 7) * 32 + (bid >> 3);
    int m0 = (bs >> 3) * 256, n0 = (bs & 7) * 256;

    int swz = (kq ^ ((rlo >> 1) & 3)) * 16;
    int ab = (wm * 128 + rlo) * 64 + swz;
    int bb = 16384 + (wn * 64 + rlo) * 64 + swz;

    int r0 = tid >> 2;
    int ps = tid & 3;
    int ssw = (ps ^ ((r0 >> 1) & 3)) * 8;
    const us* pA = A + (size_t)(m0 + r0) * K_EXT + ssw;
    const us* pB = B + (size_t)(n0 + r0) * K_EXT + ssw;
    char* lw0 = smem + w * 1024;
    char* lw1 = lw0 + 65536;
    const char* sm0 = smem;
    const char* sm1 = smem + 65536;

    floatx4 acc[8][4];
#pragma unroll
    for (int mi = 0; mi < 8; ++mi)
#pragma unroll
        for (int ni = 0; ni < 4; ++ni) acc[mi][ni] = (floatx4)0.f;

    stage2(pA,      lw0);
    stage2(pB,      lw0 + 16384);
    stage2(pA + 32, lw0 + 32768);
    stage2(pB + 32, lw0 + 49152);
    stage2(pA + 64, lw1);
    stage2(pB + 64, lw1 + 16384);
    stage2(pB + 96, lw1 + 49152);
    asm volatile("s_waitcnt vmcnt(10)" ::: "memory");
    __builtin_amdgcn_s_barrier();

    short8 afA[4], afB[4], bfA[4], bfB[4];
#pragma unroll
    for (int i = 0; i < 4; ++i) afA[i] = *(const short8*)(sm0 + ab + i * 1024);
#pragma unroll
    for (int i = 0; i < 4; ++i) bfA[i] = *(const short8*)(sm0 + bb + i * 1024);

    for (int tt = 0; tt < 16; ++tt) {
        int t0 = tt * 2;
        ktile<0xF, 8, 8, true>(pA, pB, (t0 + 1) * 64, (t0 + 2) * 64,
                               sm0, sm1, lw0, lw1, ab, bb, afA, afB, bfA, bfB, acc);
        ktile<0xF, 8, 8, true>(pA, pB, (t0 + 2) * 64, (t0 + 3) * 64,
                               sm1, sm0, lw1, lw0, ab, bb, afA, afB, bfA, bfB, acc);
    }
    ktile<0x1, 8, 4, true>(pA, pB, 33 * 64, 34 * 64,
                           sm0, sm1, lw0, lw1, ab, bb, afA, afB, bfA, bfB, acc);
    ktile<0x0, 0, -1, false>(pA, pB, 0, 0,
                             sm1, sm0, lw1, lw0, ab, bb, afA, afB, bfA, bfB, acc);

    float bbias[4];
#pragma unroll
    for (int ni = 0; ni < 4; ++ni) bbias[ni] = bias[n0 + wn * 64 + ni * 16 + rlo];
#pragma unroll
    for (int mi = 0; mi < 8; ++mi) {
        int row = m0 + wm * 128 + mi * 16 + kq * 4;
#pragma unroll
        for (int ni = 0; ni < 4; ++ni) {
            int col = n0 + wn * 64 + ni * 16 + rlo;
#pragma unroll
            for (int r = 0; r < 4; ++r)
                out[(size_t)(row + r) * OUT_DIM + col] = acc[mi][ni][r] + bbias[ni];
        }
    }
}

// ---------------------------------------------------------------------------
// Fused cooperative kernel: P1 prep | grid.sync | P2 T-GEMM | grid.sync | P3.
// ---------------------------------------------------------------------------
__global__ __launch_bounds__(512) void fused_all(
    const float* __restrict__ x, const float* __restrict__ routing,
    const float* __restrict__ W, const float* __restrict__ bias,
    const float* __restrict__ As, const float* __restrict__ Bs,
    const float* __restrict__ Ae, const float* __restrict__ Be,
    float* __restrict__ out, us* __restrict__ Aext, us* __restrict__ Bext,
    us* __restrict__ AcatT)
{
    extern __shared__ char smem[];
    int tid = threadIdx.x;
    int bid = blockIdx.x;

    // ------------------ P1: streaming conversions ------------------
    {
        int half = tid >> 8;          // 0..1
        int t = tid & 255;
        int col = t * 8;
        // x rows bid*32..+32 -> bf16 panel (coalesced: lanes stride 32B)
#pragma unroll 4
        for (int rr = 0; rr < 16; ++rr) {
            int row = bid * 32 + rr * 2 + half;
            const float4* src = (const float4*)(x + (size_t)row * IN_DIM + col);
            *(short8*)(Aext + (size_t)row * K_EXT + col) = cvt8(src[0], src[1]);
        }
        // W rows bid*8..+8 -> Bext
#pragma unroll
        for (int rr = 0; rr < 4; ++rr) {
            int n = bid * 8 + rr * 2 + half;
            const float4* src = (const float4*)(W + (size_t)n * IN_DIM + col);
            *(short8*)(Bext + (size_t)n * K_EXT + col) = cvt8(src[0], src[1]);
        }
        // Bext rank cols (8 rows x 128 cols)
#pragma unroll
        for (int it = 0; it < 2; ++it) {
            int q = it * 512 + tid;
            int rrow = q >> 7, ccol = q & 127;
            int n = bid * 8 + rrow;
            float v = 0.f;
            if (ccol < 8)       v = Bs[(size_t)ccol * OUT_DIM + n];
            else if (ccol < 72) v = Be[(size_t)(ccol - 8) * OUT_DIM + n];
            Bext[(size_t)n * K_EXT + IN_DIM + ccol] = f2bf(v);
        }
        // AcatT row kp = bid (blocks 0..95): col i = elem [i][kp] of [A_s|A_e]
        if (bid < 96) {
            int kp = bid;
            int i0 = tid * 4;
#pragma unroll
            for (int j = 0; j < 4; ++j) {
                int i = i0 + j;
                float v = 0.f;
                if (kp < 8)       v = As[(size_t)i * 8 + kp];
                else if (kp < 72) v = Ae[(size_t)(kp - 8) + (size_t)i * 8
                                         + (size_t)((kp - 8) >> 3) * (IN_DIM * 8 - 8)
                                         + (size_t)0];
                AcatT[(size_t)kp * IN_DIM + i] = f2bf(v);
            }
        }
    }

    cg::grid_group grid = cg::this_grid();
    __threadfence();
    grid.sync();
    __threadfence();

    // ------------------ P2: T = xbf16 @ A_cat, routed -> Aext rank cols -----
    {
        floatx4* red = (floatx4*)smem;    // [8 waves][64 lanes][12 frags]
        int lane = tid & 63, w = tid >> 6;
        int rlo = lane & 15, kq = lane >> 4;
        int mbase = bid * 32;

        floatx4 acc[2][6];
#pragma unroll
        for (int rg = 0; rg < 2; ++rg)
#pragma unroll
            for (int ni = 0; ni < 6; ++ni) acc[rg][ni] = (floatx4)0.f;

        const us* a0p = Aext + (size_t)(mbase + rlo) * K_EXT + w * 256 + kq * 8;
        const us* a1p = Aext + (size_t)(mbase + 16 + rlo) * K_EXT + w * 256 + kq * 8;
        const us* b0p = AcatT + (size_t)rlo * IN_DIM + w * 256 + kq * 8;

#pragma unroll
        for (int kt = 0; kt < 8; ++kt) {
            int k0 = kt * 32;
            short8 a0 = *(const short8*)(a0p + k0);
            short8 a1 = *(const short8*)(a1p + k0);
#pragma unroll
            for (int ni = 0; ni < 6; ++ni) {
                short8 bfr = *(const short8*)(b0p + (size_t)(ni * 16) * IN_DIM + k0);
                acc[0][ni] = __builtin_amdgcn_mfma_f32_16x16x32_bf16(a0, bfr, acc[0][ni], 0, 0, 0);
                acc[1][ni] = __builtin_amdgcn_mfma_f32_16x16x32_bf16(a1, bfr, acc[1][ni], 0, 0, 0);
            }
        }
#pragma unroll
        for (int rg = 0; rg < 2; ++rg)
#pragma unroll
            for (int ni = 0; ni < 6; ++ni)
                red[(w * 64 + lane) * 12 + rg * 6 + ni] = acc[rg][ni];
        __syncthreads();
        if (w < 2) {
            int rg = w;
#pragma unroll
            for (int ni = 0; ni < 6; ++ni) {
                floatx4 s = red[lane * 12 + rg * 6 + ni];
#pragma unroll
                for (int ww = 1; ww < 8; ++ww)
                    s += red[(ww * 64 + lane) * 12 + rg * 6 + ni];
                int col = ni * 16 + rlo;
#pragma unroll
                for (int r = 0; r < 4; ++r) {
                    int row = mbase + rg * 16 + kq * 4 + r;
                    float fac = (col < 8) ? 1.f
                              : (col < 72 ? routing[(row >> 11) * NE + ((col - 8) >> 3)] : 0.f);
                    Aext[(size_t)row * K_EXT + IN_DIM + col] = f2bf(s[r] * fac);
                }
            }
#pragma unroll
            for (int c = 0; c < 2; ++c) {
                int col = 96 + c * 16 + rlo;
#pragma unroll
                for (int r = 0; r < 4; ++r)
                    Aext[(size_t)(mbase + rg * 16 + kq * 4 + r) * K_EXT + IN_DIM + col] = 0;
            }
        }
    }

    __threadfence();
    grid.sync();
    __threadfence();

    // ------------------ P3: main GEMM ------------------
    run_main_gemm(smem, tid, bid, Aext, Bext, bias, out);
}

extern "C" void kernel_launch(void* const* d_in, const int* in_sizes, int n_in,
                              void* d_out, int out_size, void* d_ws, size_t ws_size,
                              hipStream_t stream) {
    const float* x   = (const float*)d_in[0];
    const float* rw  = (const float*)d_in[1];
    const float* W   = (const float*)d_in[2];
    const float* bv  = (const float*)d_in[3];
    const float* As  = (const float*)d_in[4];
    const float* Bs  = (const float*)d_in[5];
    const float* Ae  = (const float*)d_in[6];
    const float* Be  = (const float*)d_in[7];
    float* out = (float*)d_out;

    size_t offA = 0;
    size_t offB = offA + (size_t)M_TOT * K_EXT * sizeof(us);
    size_t offC = offB + (size_t)OUT_DIM * K_EXT * sizeof(us);
    size_t need = offC + (size_t)96 * IN_DIM * sizeof(us);
    if (ws_size < need) return;

    us* Aext  = (us*)((char*)d_ws + offA);
    us* Bext  = (us*)((char*)d_ws + offB);
    us* AcatT = (us*)((char*)d_ws + offC);

    hipFuncSetAttribute((const void*)fused_all,
                        hipFuncAttributeMaxDynamicSharedMemorySize, 131072);

    void* args[] = {(void*)&x, (void*)&rw, (void*)&W, (void*)&bv,
                    (void*)&As, (void*)&Bs, (void*)&Ae, (void*)&Be,
                    (void*)&out, (void*)&Aext, (void*)&Bext, (void*)&AcatT};
    hipLaunchCooperativeKernel((void*)fused_all, dim3(256), dim3(512),
                               args, 131072, stream);
}

// Round 8
// 115.058 us; speedup vs baseline: 2.9925x; 2.9925x over previous
//
#include <hip/hip_runtime.h>
#include <hip/hip_bf16.h>

#define IN_DIM 2048
#define OUT_DIM 2048
#define NE 8
#define M_TOT 8192          // B*S = 4*2048
#define RANK_PAD 128        // 8 shared + 64 expert + 24 zero + 32 align pad
#define K_EXT 2176          // IN_DIM + RANK_PAD, divisible by 64

typedef short short4v __attribute__((ext_vector_type(4)));
typedef short short8 __attribute__((ext_vector_type(8)));
typedef float floatx4 __attribute__((ext_vector_type(4)));
typedef unsigned short us;

__device__ __forceinline__ us f2bf(float f) {
    __hip_bfloat16 h = __float2bfloat16(f);   // native RNE cast
    return *reinterpret_cast<us*>(&h);
}

__device__ __forceinline__ void gld_lds16(const void* g, void* l) {
    __builtin_amdgcn_global_load_lds(
        (const __attribute__((address_space(1))) void*)g,
        (__attribute__((address_space(3))) void*)l, 16, 0, 0);
}

// ---------------------------------------------------------------------------
// Main GEMM — EXACT R4/R6 kernel (proven 68.4us, 0 bank conflicts, 45% Mfma).
// 256x256 tile, 8-phase read-ahead, counted lgkm(4/8), vmcnt(8) at p0/p2,
// slot swizzle ps = s ^ ((row>>1)&3) both sides, XCD-chunked block swizzle.
// ---------------------------------------------------------------------------

__device__ __forceinline__ void stage2(const us* src, char* lds) {
    gld_lds16(src, lds);
    gld_lds16(src + 128 * K_EXT, lds + 8192);
}

__device__ __forceinline__ void mfma_quad(floatx4 (&acc)[8][4], const short8 (&af)[4],
                                          const short8 (&bf)[4], int mq) {
#pragma unroll
    for (int i = 0; i < 4; ++i)
#pragma unroll
        for (int ni = 0; ni < 4; ++ni)
            acc[mq * 4 + i][ni] =
                __builtin_amdgcn_mfma_f32_16x16x32_bf16(af[i], bf[ni], acc[mq * 4 + i][ni], 0, 0, 0);
}

template <int SM, int VM0, int VM2, bool RD3>
__device__ __forceinline__ void ktile(
    const us* __restrict__ pA, const us* __restrict__ pB, int k1, int k2,
    const char* smC, const char* smN, char* lwC, char* lwN,
    int ab, int bb,
    short8 (&afA)[4], short8 (&afB)[4], short8 (&bfA)[4], short8 (&bfB)[4],
    floatx4 (&acc)[8][4])
{
    // ---------- p0 ----------
#pragma unroll
    for (int i = 0; i < 4; ++i) afB[i] = *(const short8*)(smC + ab + (4 + i) * 1024);
    asm volatile("s_waitcnt lgkmcnt(4)" ::: "memory");
    __builtin_amdgcn_sched_barrier(0);
    __builtin_amdgcn_s_setprio(1);
    mfma_quad(acc, afA, bfA, 0);
    __builtin_amdgcn_s_setprio(0);
    if (SM & 1) stage2(pA + k1 + 32, lwN + 32768);
    if (VM0 == 8)      asm volatile("s_waitcnt vmcnt(8)" ::: "memory");
    else if (VM0 == 0) asm volatile("s_waitcnt vmcnt(0)" ::: "memory");
    __builtin_amdgcn_s_barrier();

    // ---------- p1 ----------
#pragma unroll
    for (int i = 0; i < 4; ++i) afA[i] = *(const short8*)(smC + 32768 + ab + (4 + i) * 1024);
#pragma unroll
    for (int i = 0; i < 4; ++i) bfB[i] = *(const short8*)(smC + 32768 + bb + i * 1024);
    asm volatile("s_waitcnt lgkmcnt(8)" ::: "memory");
    __builtin_amdgcn_sched_barrier(0);
    __builtin_amdgcn_s_setprio(1);
    mfma_quad(acc, afB, bfA, 1);
    __builtin_amdgcn_s_setprio(0);
    if (SM & 2) stage2(pB + k2, lwC + 16384);
    __builtin_amdgcn_s_barrier();

    // ---------- p2 ----------
#pragma unroll
    for (int i = 0; i < 4; ++i) afB[i] = *(const short8*)(smC + 32768 + ab + i * 1024);
    asm volatile("s_waitcnt lgkmcnt(4)" ::: "memory");
    __builtin_amdgcn_sched_barrier(0);
    __builtin_amdgcn_s_setprio(1);
    mfma_quad(acc, afA, bfB, 1);
    __builtin_amdgcn_s_setprio(0);
    if (SM & 4) stage2(pA + k2, lwC);
    if (VM2 == 8)      asm volatile("s_waitcnt vmcnt(8)" ::: "memory");
    else if (VM2 == 4) asm volatile("s_waitcnt vmcnt(4)" ::: "memory");
    __builtin_amdgcn_s_barrier();

    // ---------- p3 ----------
    if (RD3) {
#pragma unroll
        for (int i = 0; i < 4; ++i) afA[i] = *(const short8*)(smN + ab + i * 1024);
#pragma unroll
        for (int i = 0; i < 4; ++i) bfA[i] = *(const short8*)(smN + bb + i * 1024);
        asm volatile("s_waitcnt lgkmcnt(8)" ::: "memory");
    } else {
        asm volatile("s_waitcnt lgkmcnt(0)" ::: "memory");
    }
    __builtin_amdgcn_sched_barrier(0);
    __builtin_amdgcn_s_setprio(1);
    mfma_quad(acc, afB, bfB, 0);
    __builtin_amdgcn_s_setprio(0);
    if (SM & 8) stage2(pB + k2 + 32, lwC + 49152);
    __builtin_amdgcn_s_barrier();
}

__global__ __launch_bounds__(512) void main_gemm8(const us* __restrict__ A,
                                                  const us* __restrict__ B,
                                                  const float* __restrict__ bias,
                                                  float* __restrict__ out) {
    extern __shared__ char smem[];
    int tid = threadIdx.x;
    int lane = tid & 63, w = tid >> 6;
    int wm = w >> 2, wn = w & 3;          // 2M x 4N waves; per-wave C = 128x64
    int rlo = lane & 15, kq = lane >> 4;

    // XCD-chunked swizzle: 256 blocks = 8 XCDs x 32
    int b = blockIdx.x;
    int bs = (b & 7) * 32 + (b >> 3);
    int m0 = (bs >> 3) * 256, n0 = (bs & 7) * 256;

    int swz = (kq ^ ((rlo >> 1) & 3)) * 16;
    int ab = (wm * 128 + rlo) * 64 + swz;            // + mi*1024 + kh*32768
    int bb = 16384 + (wn * 64 + rlo) * 64 + swz;     // + ni*1024 + kh*32768

    // staging source pointers (pre-swizzled global, rule #21)
    int r0 = tid >> 2;
    int ps = tid & 3;
    int ssw = (ps ^ ((r0 >> 1) & 3)) * 8;
    const us* pA = A + (size_t)(m0 + r0) * K_EXT + ssw;
    const us* pB = B + (size_t)(n0 + r0) * K_EXT + ssw;
    char* lw0 = smem + w * 1024;
    char* lw1 = lw0 + 65536;
    const char* sm0 = smem;
    const char* sm1 = smem + 65536;

    floatx4 acc[8][4];
#pragma unroll
    for (int mi = 0; mi < 8; ++mi)
#pragma unroll
        for (int ni = 0; ni < 4; ++ni) acc[mi][ni] = (floatx4)0.f;

    // prologue: 7 halves (tile0 complete; tile1 A.K0,B.K0,B.K1)
    stage2(pA,      lw0);              // A.K0(0)
    stage2(pB,      lw0 + 16384);      // B.K0(0)
    stage2(pA + 32, lw0 + 32768);      // A.K1(0)
    stage2(pB + 32, lw0 + 49152);      // B.K1(0)
    stage2(pA + 64, lw1);              // A.K0(1)
    stage2(pB + 64, lw1 + 16384);      // B.K0(1)
    stage2(pB + 96, lw1 + 49152);      // B.K1(1)
    asm volatile("s_waitcnt vmcnt(10)" ::: "memory");   // tile0 A.K0/B.K0 landed
    __builtin_amdgcn_s_barrier();

    short8 afA[4], afB[4], bfA[4], bfB[4];
#pragma unroll
    for (int i = 0; i < 4; ++i) afA[i] = *(const short8*)(sm0 + ab + i * 1024);
#pragma unroll
    for (int i = 0; i < 4; ++i) bfA[i] = *(const short8*)(sm0 + bb + i * 1024);

    for (int tt = 0; tt < 16; ++tt) {
        int t0 = tt * 2;
        ktile<0xF, 8, 8, true>(pA, pB, (t0 + 1) * 64, (t0 + 2) * 64,
                               sm0, sm1, lw0, lw1, ab, bb, afA, afB, bfA, bfB, acc);
        ktile<0xF, 8, 8, true>(pA, pB, (t0 + 2) * 64, (t0 + 3) * 64,
                               sm1, sm0, lw1, lw0, ab, bb, afA, afB, bfA, bfB, acc);
    }
    ktile<0x1, 8, 4, true>(pA, pB, 33 * 64, 34 * 64,
                           sm0, sm1, lw0, lw1, ab, bb, afA, afB, bfA, bfB, acc);
    ktile<0x0, 0, -1, false>(pA, pB, 0, 0,
                             sm1, sm0, lw1, lw0, ab, bb, afA, afB, bfA, bfB, acc);

    // epilogue: C/D map col=rlo, row=kq*4+reg
    float bbias[4];
#pragma unroll
    for (int ni = 0; ni < 4; ++ni) bbias[ni] = bias[n0 + wn * 64 + ni * 16 + rlo];
#pragma unroll
    for (int mi = 0; mi < 8; ++mi) {
        int row = m0 + wm * 128 + mi * 16 + kq * 4;
#pragma unroll
        for (int ni = 0; ni < 4; ++ni) {
            int col = n0 + wn * 64 + ni * 16 + rlo;
#pragma unroll
            for (int r = 0; r < 4; ++r)
                out[(size_t)(row + r) * OUT_DIM + col] = acc[mi][ni][r] + bbias[ni];
        }
    }
}

// ---------------------------------------------------------------------------
// prep_acat: A_catT[96][2048] bf16; row k' = column k' of [A_s | A_e...].
// Must precede prep_tgemm (which reads AcatT). ~3us.
// ---------------------------------------------------------------------------
__global__ void prep_acat(const float* __restrict__ As, const float* __restrict__ Ae,
                          us* __restrict__ AcatT) {
    int kp = blockIdx.x;          // 0..95
    int i0 = threadIdx.x * 8;
    short8 o;
#pragma unroll
    for (int j = 0; j < 8; ++j) {
        int i = i0 + j;
        float v = 0.f;
        if (kp < 8)       v = As[(size_t)i * 8 + kp];
        else if (kp < 72) v = Ae[(size_t)((kp - 8) >> 3) * IN_DIM * 8 + (size_t)i * 8 + ((kp - 8) & 7)];
        o[j] = (short)f2bf(v);
    }
    *(short8*)(AcatT + (size_t)kp * IN_DIM + i0) = o;
}

// ---------------------------------------------------------------------------
// prep_tgemm (R8): one launch, two block roles.
//  blocks 0..511   : tgemm (R6 body) — x->bf16 panel + rank-96 T with routing.
//  blocks 512..1023: W conversion -> Bext rows (4 rows/block) + rank cols.
// The W-stream blocks fill CU idle slots while tgemm blocks stall on L2.
// ---------------------------------------------------------------------------
__global__ __launch_bounds__(512) void prep_tgemm(
    const float* __restrict__ x, us* __restrict__ Aext,
    const us* __restrict__ AcatT, const float* __restrict__ routing,
    const float* __restrict__ W, const float* __restrict__ Bs,
    const float* __restrict__ Be, us* __restrict__ Bext)
{
    __shared__ floatx4 red[8][64][6];
    int tid = threadIdx.x;
    int bid = blockIdx.x;

    if (bid >= 512) {
        // ---- W conversion: 4 rows per block ----
        int base = (bid - 512) * 4;
        int half = tid >> 8;          // 0..1
        int t = tid & 255;
        int col = t * 8;
#pragma unroll
        for (int rr = 0; rr < 2; ++rr) {
            int n = base + rr * 2 + half;
            const float4* src = (const float4*)(W + (size_t)n * IN_DIM + col);
            float4 v0 = src[0], v1 = src[1];
            short8 o;
            o[0] = (short)f2bf(v0.x); o[1] = (short)f2bf(v0.y);
            o[2] = (short)f2bf(v0.z); o[3] = (short)f2bf(v0.w);
            o[4] = (short)f2bf(v1.x); o[5] = (short)f2bf(v1.y);
            o[6] = (short)f2bf(v1.z); o[7] = (short)f2bf(v1.w);
            *(short8*)(Bext + (size_t)n * K_EXT + col) = o;
        }
        // rank cols: 4 rows x 128 cols = 512 writes, one per thread
        int rrow = tid >> 7, ccol = tid & 127;
        int n = base + rrow;
        float v = 0.f;
        if (ccol < 8)       v = Bs[(size_t)ccol * OUT_DIM + n];
        else if (ccol < 72) v = Be[(size_t)(ccol - 8) * OUT_DIM + n];
        Bext[(size_t)n * K_EXT + IN_DIM + ccol] = f2bf(v);
        return;
    }

    // ---- tgemm: 16 rows per block, K split 8 ways ----
    int lane = tid & 63, w = tid >> 6;     // wave w owns K range [w*256, +256)
    int rlo = lane & 15, kq = lane >> 4;
    int mbase = bid * 16;

    floatx4 acc[6];
#pragma unroll
    for (int ni = 0; ni < 6; ++ni) acc[ni] = (floatx4)0.f;

    const float* xrow = x + (size_t)(mbase + rlo) * IN_DIM + w * 256 + kq * 8;
    us* arow = Aext + (size_t)(mbase + rlo) * K_EXT + w * 256 + kq * 8;
    const us* bbase = AcatT + (size_t)rlo * IN_DIM + w * 256 + kq * 8;

#pragma unroll
    for (int kt = 0; kt < 8; ++kt) {
        int k0 = kt * 32;
        float4 v0 = *(const float4*)(xrow + k0);
        float4 v1 = *(const float4*)(xrow + k0 + 4);
        short8 a;
        a[0] = (short)f2bf(v0.x); a[1] = (short)f2bf(v0.y);
        a[2] = (short)f2bf(v0.z); a[3] = (short)f2bf(v0.w);
        a[4] = (short)f2bf(v1.x); a[5] = (short)f2bf(v1.y);
        a[6] = (short)f2bf(v1.z); a[7] = (short)f2bf(v1.w);
        *(short8*)(arow + k0) = a;
#pragma unroll
        for (int ni = 0; ni < 6; ++ni) {
            short8 bfr = *(const short8*)(bbase + (size_t)(ni * 16) * IN_DIM + k0);
            acc[ni] = __builtin_amdgcn_mfma_f32_16x16x32_bf16(a, bfr, acc[ni], 0, 0, 0);
        }
    }

#pragma unroll
    for (int ni = 0; ni < 6; ++ni) red[w][lane][ni] = acc[ni];
    __syncthreads();
    if (w == 0) {
#pragma unroll
        for (int ni = 0; ni < 6; ++ni) {
            floatx4 s = red[0][lane][ni];
#pragma unroll
            for (int ww = 1; ww < 8; ++ww) s += red[ww][lane][ni];
            int col = ni * 16 + rlo;
#pragma unroll
            for (int r = 0; r < 4; ++r) {
                int row = mbase + kq * 4 + r;
                float fac = (col < 8) ? 1.f
                          : (col < 72 ? routing[(row >> 11) * NE + ((col - 8) >> 3)] : 0.f);
                Aext[(size_t)row * K_EXT + IN_DIM + col] = f2bf(s[r] * fac);
            }
        }
#pragma unroll
        for (int c = 0; c < 2; ++c) {
            int col = 96 + c * 16 + rlo;
#pragma unroll
            for (int r = 0; r < 4; ++r)
                Aext[(size_t)(mbase + kq * 4 + r) * K_EXT + IN_DIM + col] = 0;
        }
    }
}

extern "C" void kernel_launch(void* const* d_in, const int* in_sizes, int n_in,
                              void* d_out, int out_size, void* d_ws, size_t ws_size,
                              hipStream_t stream) {
    const float* x   = (const float*)d_in[0];
    const float* rw  = (const float*)d_in[1];
    const float* W   = (const float*)d_in[2];
    const float* bv  = (const float*)d_in[3];
    const float* As  = (const float*)d_in[4];
    const float* Bs  = (const float*)d_in[5];
    const float* Ae  = (const float*)d_in[6];
    const float* Be  = (const float*)d_in[7];
    float* out = (float*)d_out;

    size_t offA = 0;
    size_t offB = offA + (size_t)M_TOT * K_EXT * sizeof(us);
    size_t offC = offB + (size_t)OUT_DIM * K_EXT * sizeof(us);
    size_t need = offC + (size_t)96 * IN_DIM * sizeof(us);
    if (ws_size < need) return;

    us* Aext  = (us*)((char*)d_ws + offA);
    us* Bext  = (us*)((char*)d_ws + offB);
    us* AcatT = (us*)((char*)d_ws + offC);

    hipFuncSetAttribute((const void*)main_gemm8,
                        hipFuncAttributeMaxDynamicSharedMemorySize, 131072);

    prep_acat<<<96, 256, 0, stream>>>(As, Ae, AcatT);
    prep_tgemm<<<1024, 512, 0, stream>>>(x, Aext, AcatT, rw, W, Bs, Be, Bext);
    main_gemm8<<<256, 512, 131072, stream>>>(Aext, Bext, bv, out);
}